// Round 17
// baseline (120.078 us; speedup 1.0000x reference)
//
#include <hip/hip_runtime.h>

#define DD 128

typedef __attribute__((ext_vector_type(8))) short bf16x8;
typedef __attribute__((ext_vector_type(4))) float f32x4;

__device__ __forceinline__ unsigned int cvt_pk_bf16(float lo, float hi) {
  unsigned int r;
  asm("v_cvt_pk_bf16_f32 %0, %1, %2" : "=v"(r) : "v"(lo), "v"(hi));
  return r;
}
__device__ __forceinline__ float bf_lo(unsigned int v) { return __uint_as_float(v << 16); }
__device__ __forceinline__ float bf_hi(unsigned int v) { return __uint_as_float(v & 0xFFFF0000u); }

// ---------------------------------------------------------------------------
// prep v7: xq4 = biased-int8(x) in QUARTER-MAJOR layout (4 slices of [N][32],
// each slice 3.2MB -> fits per-XCD L2); sx[n] per-row scale; CSR; B table.
// ---------------------------------------------------------------------------
__global__ __launch_bounds__(256) void prep_kernel(
    const float* __restrict__ x, const int* __restrict__ dst,
    const float* __restrict__ W, const float* __restrict__ KG,
    unsigned char* __restrict__ xq4, float* __restrict__ sx,
    int* __restrict__ row_start, unsigned short* __restrict__ B,
    int N, int E, int ABLK, int BBLK) {
  int blk = blockIdx.x;
  int t = threadIdx.x;
  if (blk < ABLK) {
    int n = blk * 16 + (t >> 4);
    int lr = t & 15;
    if (n < N) {
      const float4* xr = (const float4*)(x + (size_t)n * DD);
      float4 va = xr[lr * 2], vb = xr[lr * 2 + 1];
      float m = fmaxf(fmaxf(fmaxf(fabsf(va.x), fabsf(va.y)), fmaxf(fabsf(va.z), fabsf(va.w))),
                      fmaxf(fmaxf(fabsf(vb.x), fabsf(vb.y)), fmaxf(fabsf(vb.z), fabsf(vb.w))));
#pragma unroll
      for (int d = 1; d < 16; d <<= 1) m = fmaxf(m, __shfl_xor(m, d, 16));
      m = fmaxf(m, 1e-20f);
      float inv = 127.0f / m;
      unsigned int q0 = (unsigned int)(__float2int_rn(va.x * inv) + 128);
      unsigned int q1 = (unsigned int)(__float2int_rn(va.y * inv) + 128);
      unsigned int q2 = (unsigned int)(__float2int_rn(va.z * inv) + 128);
      unsigned int q3 = (unsigned int)(__float2int_rn(va.w * inv) + 128);
      unsigned int q4 = (unsigned int)(__float2int_rn(vb.x * inv) + 128);
      unsigned int q5 = (unsigned int)(__float2int_rn(vb.y * inv) + 128);
      unsigned int q6 = (unsigned int)(__float2int_rn(vb.z * inv) + 128);
      unsigned int q7 = (unsigned int)(__float2int_rn(vb.w * inv) + 128);
      uint2 qp;
      qp.x = q0 | (q1 << 8) | (q2 << 16) | (q3 << 24);
      qp.y = q4 | (q5 << 8) | (q6 << 16) | (q7 << 24);
      // lane lr covers features lr*8..lr*8+7 -> quarter lr>>2, chunk lr&3
      unsigned char* slice = xq4 + (size_t)(lr >> 2) * N * 32;
      ((uint2*)(slice + (size_t)n * 32))[lr & 3] = qp;
      if (lr == 0) sx[n] = m * (1.0f / 127.0f);
    }
  } else if (blk < ABLK + BBLK) {
    int e = (blk - ABLK) * 256 + t;
    if (e <= E) {
      if (e == 0) {
        int d0 = dst[0];
        for (int n = 0; n <= d0; ++n) row_start[n] = 0;
      } else if (e == E) {
        for (int n = dst[E - 1] + 1; n <= N; ++n) row_start[n] = E;
      } else {
        int d = dst[e], dp = dst[e - 1];
        for (int n = dp + 1; n <= d; ++n) row_start[n] = e;
      }
    }
  } else {
    int e2 = (blk - ABLK - BBLK) * 256 + t;
    if (e2 < 2 * DD * DD) {
      int j = e2 >> 7, k = e2 & 127;
      float v = (j < DD) ? W[j * DD + k] : KG[k * DD + (j - DD)];
      B[e2] = (unsigned short)cvt_pk_bf16(v, v);
    }
  }
}

// ---------------------------------------------------------------------------
// scatter_agg_q: one feature-quarter per launch. Slice (3.2MB) becomes
// L2-resident in every XCD -> gathers are L2 hits, not fabric misses.
// 8 nodes/wave (8 lanes each, uint = 4B/lane -> 32B row); 4-edge unroll.
// ---------------------------------------------------------------------------
__global__ __launch_bounds__(256, 8) void scatter_agg_q(
    const unsigned char* __restrict__ xq4, const float* __restrict__ sx,
    const int* __restrict__ src, const float* __restrict__ ew,
    const int* __restrict__ row_start, unsigned short* __restrict__ aggb,
    float* __restrict__ sumw, int N, int E, int qq) {
  int t = threadIdx.x;
  int wid = t >> 6, lane = t & 63;
  int g = lane >> 3, lr = lane & 7;
  int n = blockIdx.x * 32 + wid * 8 + g;
  bool valid = (n < N);
  int b = valid ? row_start[n] : 0;
  int cnt = valid ? (row_start[n + 1] - b) : 0;
  const unsigned int* xs = (const unsigned int*)(xq4 + (size_t)qq * N * 32);

  float a[4] = {0.f, 0.f, 0.f, 0.f};
  float wsum = 0.f, wsc = 0.f;
  int clampj = cnt > 0 ? cnt - 1 : 0;

  int i = 0;
  while (__any(i < cnt)) {
#pragma unroll
    for (int u = 0; u < 4; ++u) {
      int ii = i + u;
      int jj = ii < clampj ? ii : clampj;
      int j = b + jj;
      if (j > E - 1) j = E - 1;
      float wt = (ii < cnt) ? ew[j] : 0.f;
      int s = src[j];
      float ws = wt * sx[s];
      unsigned int v = xs[(size_t)s * 8 + lr];
      wsum += wt;
      wsc += ws;
      a[0] += ws * (float)(v & 0xFF);
      a[1] += ws * (float)((v >> 8) & 0xFF);
      a[2] += ws * (float)((v >> 16) & 0xFF);
      a[3] += ws * (float)(v >> 24);
    }
    i += 4;
  }
  float c = 128.0f * wsc;
#pragma unroll
  for (int k = 0; k < 4; ++k) a[k] -= c;

  if (valid) {
    uint2 o;
    o.x = cvt_pk_bf16(a[0], a[1]);
    o.y = cvt_pk_bf16(a[2], a[3]);
    *(uint2*)&aggb[(size_t)n * DD + qq * 32 + lr * 4] = o;
    if (lr == 0 && qq == 0) sumw[n] = wsum;
  }
}

// ---------------------------------------------------------------------------
// fused_gemm v5b (r15 best): per 64-node tile:
//   S = relu(aggb @ W^T + sumw*b);  G = sigmoid(x @ KG + bg);
//   out = G*S + (1-G)*x
// x tile staged from quarter-major xq4 (same feature mapping, new addresses).
// Persistent weights; paired NT f32x4 epilogue stores.
// ---------------------------------------------------------------------------
__global__ __launch_bounds__(256, 3) void fused_gemm(
    const unsigned char* __restrict__ xq4, const float* __restrict__ sx,
    const unsigned short* __restrict__ aggb, const unsigned short* __restrict__ B,
    const float* __restrict__ sumw, const float* __restrict__ bias,
    const float* __restrict__ bg, float* __restrict__ out, int N) {
  __shared__ char smem[32 * 1024];
  unsigned short* sX = (unsigned short*)smem;            // 16KB: x tile bf16 (swz)
  unsigned short* sA = (unsigned short*)(smem + 16384);  // 16KB: agg tile (swz)
  int t = threadIdx.x;
  int wid = t >> 6, lane = t & 63;
  int lr = lane & 15, lk2 = lane >> 4;
  int jw = wid * 32;
  int M0 = blockIdx.x * 64;

  // ---- persistent weight fragments
  bf16x8 wS[4][2], wG[4][2];  // [kc][m]
#pragma unroll
  for (int kc = 0; kc < 4; ++kc)
#pragma unroll
    for (int m = 0; m < 2; ++m) {
      int j = jw + m * 16 + lr;
      wS[kc][m] = *(const bf16x8*)(B + (size_t)j * DD + kc * 32 + lk2 * 8);
      wG[kc][m] = *(const bf16x8*)(B + (size_t)(DD + j) * DD + kc * 32 + lk2 * 8);
    }

  // ---- stage x tile from xq4: feature base = c*16 (same as before), address
  // from quarter-major layout: slice c>>1, 16B half c&1.
#pragma unroll
  for (int i = 0; i < 2; ++i) {
    int idx = i * 256 + t;
    int r = idx >> 3;           // row in tile
    int c = idx & 7;            // 16-byte chunk (feature base c*16)
    uint4 v;
    float s;
    if (M0 + r < N) {
      v = *(const uint4*)(xq4 + ((size_t)(c >> 1) * N + (M0 + r)) * 32 + (c & 1) * 16);
      s = sx[M0 + r];
    } else {
      v = make_uint4(0, 0, 0, 0);
      s = 0.f;
    }
    float nb = -128.0f * s;
    unsigned int w[4] = {v.x, v.y, v.z, v.w};
    unsigned int o[8];
#pragma unroll
    for (int q = 0; q < 4; ++q) {
      float e0 = fmaf(s, (float)(w[q] & 0xFF), nb);
      float e1 = fmaf(s, (float)((w[q] >> 8) & 0xFF), nb);
      float e2 = fmaf(s, (float)((w[q] >> 16) & 0xFF), nb);
      float e3 = fmaf(s, (float)(w[q] >> 24), nb);
      o[q * 2]     = cvt_pk_bf16(e0, e1);
      o[q * 2 + 1] = cvt_pk_bf16(e2, e3);
    }
    int base = r * 256 + c * 32;
    uint4 lo = {o[0], o[1], o[2], o[3]};
    uint4 hi = {o[4], o[5], o[6], o[7]};
    *(uint4*)((char*)sX + ((base) ^ ((r & 7) << 4)))      = lo;
    *(uint4*)((char*)sX + ((base + 16) ^ ((r & 7) << 4))) = hi;
  }
  // ---- stage agg tile (1024 uint4, swizzled)
#pragma unroll
  for (int i = 0; i < 4; ++i) {
    int idx = i * 256 + t;
    int r = idx >> 4, c = idx & 15;
    uint4 va;
    if (M0 + r < N) va = ((const uint4*)(aggb + (size_t)(M0 + r) * DD))[c];
    else            va = make_uint4(0, 0, 0, 0);
    int off = (r * 256 + c * 16) ^ ((r & 7) << 4);
    *(uint4*)((char*)sA + off) = va;
  }
  __syncthreads();

  f32x4 accS[2][4], accG[2][4];
#pragma unroll
  for (int m = 0; m < 2; ++m)
#pragma unroll
    for (int nr = 0; nr < 4; ++nr) {
      accS[m][nr] = (f32x4){0.f, 0.f, 0.f, 0.f};
      accG[m][nr] = (f32x4){0.f, 0.f, 0.f, 0.f};
    }

#pragma unroll
  for (int kc = 0; kc < 4; ++kc) {
    int kb = (kc * 32 + lk2 * 8) * 2;
    bf16x8 af[4], xf[4];
#pragma unroll
    for (int nr = 0; nr < 4; ++nr) {
      int r = nr * 16 + lr;
      int off = (r * 256 + kb) ^ ((r & 7) << 4);
      af[nr] = *(const bf16x8*)((const char*)sA + off);
      xf[nr] = *(const bf16x8*)((const char*)sX + off);
    }
#pragma unroll
    for (int m = 0; m < 2; ++m)
#pragma unroll
      for (int nr = 0; nr < 4; ++nr) {
        accS[m][nr] = __builtin_amdgcn_mfma_f32_16x16x32_bf16(wS[kc][m], af[nr], accS[m][nr], 0, 0, 0);
        accG[m][nr] = __builtin_amdgcn_mfma_f32_16x16x32_bf16(wG[kc][m], xf[nr], accG[m][nr], 0, 0, 0);
      }
  }

  // ---- epilogue: nr outer, m inner; paired NT stores.
  float ba[2][4], bga[2][4];
#pragma unroll
  for (int m = 0; m < 2; ++m) {
    int j0 = jw + m * 16 + lk2 * 4;
    *(float4*)ba[m]  = *(const float4*)&bias[j0];
    *(float4*)bga[m] = *(const float4*)&bg[j0];
  }
#pragma unroll
  for (int nr = 0; nr < 4; ++nr) {
    int node = M0 + nr * 16 + lr;
    if (node < N) {
      float sw = sumw[node];
      int r = nr * 16 + lr;
#pragma unroll
      for (int m = 0; m < 2; ++m) {
        int j0 = jw + m * 16 + lk2 * 4;
        uint2 qx = *(const uint2*)((const char*)sX + ((r * 256 + j0 * 2) ^ ((r & 7) << 4)));
        float xr[4] = {bf_lo(qx.x), bf_hi(qx.x), bf_lo(qx.y), bf_hi(qx.y)};
        f32x4 vs = accS[m][nr], vg = accG[m][nr];
        f32x4 o;
#pragma unroll
        for (int reg = 0; reg < 4; ++reg) {
          float s = fmaxf(vs[reg] + sw * ba[m][reg], 0.f);
          float g = 1.0f / (1.0f + __expf(-(vg[reg] + bga[m][reg])));
          o[reg] = g * s + (1.0f - g) * xr[reg];
        }
        __builtin_nontemporal_store(o, (f32x4*)&out[(size_t)node * DD + j0]);
      }
    }
  }
}

// ---------------------------------------------------------------------------
extern "C" void kernel_launch(void* const* d_in, const int* in_sizes, int n_in,
                              void* d_out, int out_size, void* d_ws, size_t ws_size,
                              hipStream_t stream) {
  const float* x   = (const float*)d_in[0];
  const int*   src = (const int*)d_in[1];
  const int*   dst = (const int*)d_in[2];
  const float* ew  = (const float*)d_in[3];
  const float* W   = (const float*)d_in[4];
  const float* b   = (const float*)d_in[5];
  const float* KG  = (const float*)d_in[6];
  const float* bg  = (const float*)d_in[7];
  float* out = (float*)d_out;

  int N = in_sizes[0] / DD;
  int E = in_sizes[1];

  unsigned short* aggb = (unsigned short*)d_ws;            // N*128 bf16
  unsigned char* xq4 = (unsigned char*)(aggb + (size_t)N * DD);  // 4 slices [N][32] u8
  float* sx = (float*)(xq4 + (size_t)N * DD);              // N f32
  float* sumw = sx + N;                                    // N f32
  unsigned short* B = (unsigned short*)(sumw + N);         // 2*128*128 bf16
  int* row_start = (int*)(B + 2 * DD * DD);                // N+1 ints

  int ABLK = (N + 15) / 16;
  int BBLK = (E + 1 + 255) / 256;
  int CBLK = (2 * DD * DD + 255) / 256;
  prep_kernel<<<ABLK + BBLK + CBLK, 256, 0, stream>>>(x, dst, W, KG, xq4, sx,
                                                      row_start, B, N, E, ABLK, BBLK);
  int SBLK = (N + 31) / 32;
  for (int qq = 0; qq < 4; ++qq)
    scatter_agg_q<<<SBLK, 256, 0, stream>>>(xq4, sx, src, ew, row_start, aggb, sumw, N, E, qq);
  fused_gemm<<<(N + 63) / 64, 256, 0, stream>>>(xq4, sx, aggb, B, sumw, b, bg, out, N);
}

// Round 18
// 73.425 us; speedup vs baseline: 1.6354x; 1.6354x over previous
//
#include <hip/hip_runtime.h>

#define DD 128

typedef __attribute__((ext_vector_type(8))) short bf16x8;
typedef __attribute__((ext_vector_type(4))) float f32x4;

__device__ __forceinline__ unsigned int cvt_pk_bf16(float lo, float hi) {
  unsigned int r;
  asm("v_cvt_pk_bf16_f32 %0, %1, %2" : "=v"(r) : "v"(lo), "v"(hi));
  return r;
}
__device__ __forceinline__ float bf_lo(unsigned int v) { return __uint_as_float(v << 16); }
__device__ __forceinline__ float bf_hi(unsigned int v) { return __uint_as_float(v & 0xFFFF0000u); }

// ---------------------------------------------------------------------------
// prep (r10 exact), block-partitioned jobs:
//  A (16 rows/block): xq = biased-int8(x), per-row scale sx[n]=max|x[n,:]|/127
//  B: CSR row offsets from sorted dst
//  C: B = [ W[j][k] ; KG^T[j][k] ] as bf16
// ---------------------------------------------------------------------------
__global__ __launch_bounds__(256) void prep_kernel(
    const float* __restrict__ x, const int* __restrict__ dst,
    const float* __restrict__ W, const float* __restrict__ KG,
    unsigned char* __restrict__ xq, float* __restrict__ sx,
    int* __restrict__ row_start, unsigned short* __restrict__ B,
    int N, int E, int ABLK, int BBLK) {
  int blk = blockIdx.x;
  int t = threadIdx.x;
  if (blk < ABLK) {
    int n = blk * 16 + (t >> 4);
    int lr = t & 15;
    if (n < N) {
      const float4* xr = (const float4*)(x + (size_t)n * DD);
      float4 va = xr[lr * 2], vb = xr[lr * 2 + 1];
      float m = fmaxf(fmaxf(fmaxf(fabsf(va.x), fabsf(va.y)), fmaxf(fabsf(va.z), fabsf(va.w))),
                      fmaxf(fmaxf(fabsf(vb.x), fabsf(vb.y)), fmaxf(fabsf(vb.z), fabsf(vb.w))));
#pragma unroll
      for (int d = 1; d < 16; d <<= 1) m = fmaxf(m, __shfl_xor(m, d, 16));
      m = fmaxf(m, 1e-20f);
      float inv = 127.0f / m;
      unsigned int q0 = (unsigned int)(__float2int_rn(va.x * inv) + 128);
      unsigned int q1 = (unsigned int)(__float2int_rn(va.y * inv) + 128);
      unsigned int q2 = (unsigned int)(__float2int_rn(va.z * inv) + 128);
      unsigned int q3 = (unsigned int)(__float2int_rn(va.w * inv) + 128);
      unsigned int q4 = (unsigned int)(__float2int_rn(vb.x * inv) + 128);
      unsigned int q5 = (unsigned int)(__float2int_rn(vb.y * inv) + 128);
      unsigned int q6 = (unsigned int)(__float2int_rn(vb.z * inv) + 128);
      unsigned int q7 = (unsigned int)(__float2int_rn(vb.w * inv) + 128);
      uint2 qp;
      qp.x = q0 | (q1 << 8) | (q2 << 16) | (q3 << 24);
      qp.y = q4 | (q5 << 8) | (q6 << 16) | (q7 << 24);
      ((uint2*)xq)[(size_t)n * 16 + lr] = qp;
      if (lr == 0) sx[n] = m * (1.0f / 127.0f);
    }
  } else if (blk < ABLK + BBLK) {
    int e = (blk - ABLK) * 256 + t;
    if (e <= E) {
      if (e == 0) {
        int d0 = dst[0];
        for (int n = 0; n <= d0; ++n) row_start[n] = 0;
      } else if (e == E) {
        for (int n = dst[E - 1] + 1; n <= N; ++n) row_start[n] = E;
      } else {
        int d = dst[e], dp = dst[e - 1];
        for (int n = dp + 1; n <= d; ++n) row_start[n] = e;
      }
    }
  } else {
    int e2 = (blk - ABLK - BBLK) * 256 + t;
    if (e2 < 2 * DD * DD) {
      int j = e2 >> 7, k = e2 & 127;
      float v = (j < DD) ? W[j * DD + k] : KG[k * DD + (j - DD)];
      B[e2] = (unsigned short)cvt_pk_bf16(v, v);
    }
  }
}

// ---------------------------------------------------------------------------
// scatter_agg (r10 exact): agg[n] = sum ew_e * x[src_e] via int8 table,
//   x ~ s*(u8-128);  sumw[n] = sum ew_e.
// 4 nodes/wave (16 lanes each, uint2 = 8B/lane -> 128B row); 4-edge unroll.
// 128B row = exactly one L2 line: bytes_touched == bytes_used (optimal).
// ---------------------------------------------------------------------------
__global__ __launch_bounds__(256, 8) void scatter_agg(
    const unsigned char* __restrict__ xq, const float* __restrict__ sx,
    const int* __restrict__ src, const float* __restrict__ ew,
    const int* __restrict__ row_start, unsigned short* __restrict__ aggb,
    float* __restrict__ sumw, int N, int E) {
  int t = threadIdx.x;
  int wid = t >> 6, lane = t & 63;
  int g = lane >> 4, lr = lane & 15;
  int n = blockIdx.x * 16 + wid * 4 + g;
  bool valid = (n < N);
  int b = valid ? row_start[n] : 0;
  int cnt = valid ? (row_start[n + 1] - b) : 0;
  const uint2* x8 = (const uint2*)xq;

  float a[8];
#pragma unroll
  for (int k = 0; k < 8; ++k) a[k] = 0.f;
  float wsum = 0.f, wsc = 0.f;
  int clampj = cnt > 0 ? cnt - 1 : 0;

  int i = 0;
  while (__any(i < cnt)) {
#pragma unroll
    for (int u = 0; u < 4; ++u) {
      int ii = i + u;
      int jj = ii < clampj ? ii : clampj;
      int j = b + jj;
      if (j > E - 1) j = E - 1;
      float wt = (ii < cnt) ? ew[j] : 0.f;
      int s = src[j];
      float ws = wt * sx[s];
      uint2 v = x8[(size_t)s * 16 + lr];
      wsum += wt;
      wsc += ws;
      a[0] += ws * (float)(v.x & 0xFF);
      a[1] += ws * (float)((v.x >> 8) & 0xFF);
      a[2] += ws * (float)((v.x >> 16) & 0xFF);
      a[3] += ws * (float)(v.x >> 24);
      a[4] += ws * (float)(v.y & 0xFF);
      a[5] += ws * (float)((v.y >> 8) & 0xFF);
      a[6] += ws * (float)((v.y >> 16) & 0xFF);
      a[7] += ws * (float)(v.y >> 24);
    }
    i += 4;
  }
  float c = 128.0f * wsc;
#pragma unroll
  for (int k = 0; k < 8; ++k) a[k] -= c;

  if (valid) {
    uint4 o;
    o.x = cvt_pk_bf16(a[0], a[1]);
    o.y = cvt_pk_bf16(a[2], a[3]);
    o.z = cvt_pk_bf16(a[4], a[5]);
    o.w = cvt_pk_bf16(a[6], a[7]);
    ((uint4*)aggb)[(size_t)n * 16 + lr] = o;
    if (lr == 0) sumw[n] = wsum;
  }
}

// ---------------------------------------------------------------------------
// fused_gemm v5b (r15 best): per 64-node tile:
//   S = relu(aggb @ W^T + sumw*b);  G = sigmoid(x @ KG + bg);
//   out = G*S + (1-G)*x
// Epilogue nr-outer/m-inner (64B store pairs merge to 128B lines),
// non-temporal out stores (f32x4 ext-vector), hoisted sumw/bias.
// ---------------------------------------------------------------------------
__global__ __launch_bounds__(256, 3) void fused_gemm(
    const unsigned char* __restrict__ xq, const float* __restrict__ sx,
    const unsigned short* __restrict__ aggb, const unsigned short* __restrict__ B,
    const float* __restrict__ sumw, const float* __restrict__ bias,
    const float* __restrict__ bg, float* __restrict__ out, int N) {
  __shared__ char smem[32 * 1024];
  unsigned short* sX = (unsigned short*)smem;            // 16KB: x tile bf16 (swz)
  unsigned short* sA = (unsigned short*)(smem + 16384);  // 16KB: agg tile (swz)
  int t = threadIdx.x;
  int wid = t >> 6, lane = t & 63;
  int lr = lane & 15, lk2 = lane >> 4;
  int jw = wid * 32;
  int M0 = blockIdx.x * 64;

  // ---- persistent weight fragments: W rows (support) and KG^T rows (gate)
  bf16x8 wS[4][2], wG[4][2];  // [kc][m]
#pragma unroll
  for (int kc = 0; kc < 4; ++kc)
#pragma unroll
    for (int m = 0; m < 2; ++m) {
      int j = jw + m * 16 + lr;
      wS[kc][m] = *(const bf16x8*)(B + (size_t)j * DD + kc * 32 + lk2 * 8);
      wG[kc][m] = *(const bf16x8*)(B + (size_t)(DD + j) * DD + kc * 32 + lk2 * 8);
    }

  // ---- stage x tile from xq: 512 uint4 (16 int8 each), dequant -> bf16, swz
#pragma unroll
  for (int i = 0; i < 2; ++i) {
    int idx = i * 256 + t;
    int r = idx >> 3;           // row in tile (8 uint4 per 128B row)
    int c = idx & 7;            // 16-byte chunk
    uint4 v;
    float s;
    if (M0 + r < N) {
      v = ((const uint4*)(xq + (size_t)(M0 + r) * DD))[c];
      s = sx[M0 + r];
    } else {
      v = make_uint4(0, 0, 0, 0);
      s = 0.f;
    }
    float nb = -128.0f * s;
    unsigned int w[4] = {v.x, v.y, v.z, v.w};
    unsigned int o[8];
#pragma unroll
    for (int q = 0; q < 4; ++q) {
      float e0 = fmaf(s, (float)(w[q] & 0xFF), nb);
      float e1 = fmaf(s, (float)((w[q] >> 8) & 0xFF), nb);
      float e2 = fmaf(s, (float)((w[q] >> 16) & 0xFF), nb);
      float e3 = fmaf(s, (float)(w[q] >> 24), nb);
      o[q * 2]     = cvt_pk_bf16(e0, e1);
      o[q * 2 + 1] = cvt_pk_bf16(e2, e3);
    }
    int base = r * 256 + c * 32;
    uint4 lo = {o[0], o[1], o[2], o[3]};
    uint4 hi = {o[4], o[5], o[6], o[7]};
    *(uint4*)((char*)sX + ((base) ^ ((r & 7) << 4)))      = lo;
    *(uint4*)((char*)sX + ((base + 16) ^ ((r & 7) << 4))) = hi;
  }
  // ---- stage agg tile (1024 uint4, swizzled)
#pragma unroll
  for (int i = 0; i < 4; ++i) {
    int idx = i * 256 + t;
    int r = idx >> 4, c = idx & 15;
    uint4 va;
    if (M0 + r < N) va = ((const uint4*)(aggb + (size_t)(M0 + r) * DD))[c];
    else            va = make_uint4(0, 0, 0, 0);
    int off = (r * 256 + c * 16) ^ ((r & 7) << 4);
    *(uint4*)((char*)sA + off) = va;
  }
  __syncthreads();

  f32x4 accS[2][4], accG[2][4];
#pragma unroll
  for (int m = 0; m < 2; ++m)
#pragma unroll
    for (int nr = 0; nr < 4; ++nr) {
      accS[m][nr] = (f32x4){0.f, 0.f, 0.f, 0.f};
      accG[m][nr] = (f32x4){0.f, 0.f, 0.f, 0.f};
    }

#pragma unroll
  for (int kc = 0; kc < 4; ++kc) {
    int kb = (kc * 32 + lk2 * 8) * 2;
    bf16x8 af[4], xf[4];
#pragma unroll
    for (int nr = 0; nr < 4; ++nr) {
      int r = nr * 16 + lr;
      int off = (r * 256 + kb) ^ ((r & 7) << 4);
      af[nr] = *(const bf16x8*)((const char*)sA + off);
      xf[nr] = *(const bf16x8*)((const char*)sX + off);
    }
#pragma unroll
    for (int m = 0; m < 2; ++m)
#pragma unroll
      for (int nr = 0; nr < 4; ++nr) {
        accS[m][nr] = __builtin_amdgcn_mfma_f32_16x16x32_bf16(wS[kc][m], af[nr], accS[m][nr], 0, 0, 0);
        accG[m][nr] = __builtin_amdgcn_mfma_f32_16x16x32_bf16(wG[kc][m], xf[nr], accG[m][nr], 0, 0, 0);
      }
  }

  // ---- epilogue: nr outer, m inner -> the two 64B half-row stores pair up.
  float ba[2][4], bga[2][4];
#pragma unroll
  for (int m = 0; m < 2; ++m) {
    int j0 = jw + m * 16 + lk2 * 4;
    *(float4*)ba[m]  = *(const float4*)&bias[j0];
    *(float4*)bga[m] = *(const float4*)&bg[j0];
  }
#pragma unroll
  for (int nr = 0; nr < 4; ++nr) {
    int node = M0 + nr * 16 + lr;
    if (node < N) {
      float sw = sumw[node];
      int r = nr * 16 + lr;
#pragma unroll
      for (int m = 0; m < 2; ++m) {
        int j0 = jw + m * 16 + lk2 * 4;
        uint2 qx = *(const uint2*)((const char*)sX + ((r * 256 + j0 * 2) ^ ((r & 7) << 4)));
        float xr[4] = {bf_lo(qx.x), bf_hi(qx.x), bf_lo(qx.y), bf_hi(qx.y)};
        f32x4 vs = accS[m][nr], vg = accG[m][nr];
        f32x4 o;
#pragma unroll
        for (int reg = 0; reg < 4; ++reg) {
          float s = fmaxf(vs[reg] + sw * ba[m][reg], 0.f);
          float g = 1.0f / (1.0f + __expf(-(vg[reg] + bga[m][reg])));
          o[reg] = g * s + (1.0f - g) * xr[reg];
        }
        __builtin_nontemporal_store(o, (f32x4*)&out[(size_t)node * DD + j0]);
      }
    }
  }
}

// ---------------------------------------------------------------------------
extern "C" void kernel_launch(void* const* d_in, const int* in_sizes, int n_in,
                              void* d_out, int out_size, void* d_ws, size_t ws_size,
                              hipStream_t stream) {
  const float* x   = (const float*)d_in[0];
  const int*   src = (const int*)d_in[1];
  const int*   dst = (const int*)d_in[2];
  const float* ew  = (const float*)d_in[3];
  const float* W   = (const float*)d_in[4];
  const float* b   = (const float*)d_in[5];
  const float* KG  = (const float*)d_in[6];
  const float* bg  = (const float*)d_in[7];
  float* out = (float*)d_out;

  int N = in_sizes[0] / DD;
  int E = in_sizes[1];

  unsigned short* aggb = (unsigned short*)d_ws;            // N*128 bf16
  unsigned char* xq = (unsigned char*)(aggb + (size_t)N * DD);  // N*128 u8
  float* sx = (float*)(xq + (size_t)N * DD);               // N f32
  float* sumw = sx + N;                                    // N f32
  unsigned short* B = (unsigned short*)(sumw + N);         // 2*128*128 bf16
  int* row_start = (int*)(B + 2 * DD * DD);                // N+1 ints

  int ABLK = (N + 15) / 16;
  int BBLK = (E + 1 + 255) / 256;
  int CBLK = (2 * DD * DD + 255) / 256;
  prep_kernel<<<ABLK + BBLK + CBLK, 256, 0, stream>>>(x, dst, W, KG, xq, sx,
                                                      row_start, B, N, E, ABLK, BBLK);
  scatter_agg<<<(N + 15) / 16, 256, 0, stream>>>(xq, sx, src, ew, row_start, aggb, sumw, N, E);
  fused_gemm<<<(N + 63) / 64, 256, 0, stream>>>(xq, sx, aggb, B, sumw, b, bg, out, N);
}

// Round 19
// 71.314 us; speedup vs baseline: 1.6838x; 1.0296x over previous
//
#include <hip/hip_runtime.h>

#define DD 128

typedef __attribute__((ext_vector_type(8))) short bf16x8;
typedef __attribute__((ext_vector_type(4))) float f32x4;

__device__ __forceinline__ unsigned int cvt_pk_bf16(float lo, float hi) {
  unsigned int r;
  asm("v_cvt_pk_bf16_f32 %0, %1, %2" : "=v"(r) : "v"(lo), "v"(hi));
  return r;
}
__device__ __forceinline__ float bf_lo(unsigned int v) { return __uint_as_float(v << 16); }
__device__ __forceinline__ float bf_hi(unsigned int v) { return __uint_as_float(v & 0xFFFF0000u); }

// ---------------------------------------------------------------------------
// prep (r10 exact), block-partitioned jobs:
//  A (16 rows/block): xq = biased-int8(x), per-row scale sx[n]=max|x[n,:]|/127
//  B: CSR row offsets from sorted dst
//  C: B = [ W[j][k] ; KG^T[j][k] ] as bf16
// ---------------------------------------------------------------------------
__global__ __launch_bounds__(256) void prep_kernel(
    const float* __restrict__ x, const int* __restrict__ dst,
    const float* __restrict__ W, const float* __restrict__ KG,
    unsigned char* __restrict__ xq, float* __restrict__ sx,
    int* __restrict__ row_start, unsigned short* __restrict__ B,
    int N, int E, int ABLK, int BBLK) {
  int blk = blockIdx.x;
  int t = threadIdx.x;
  if (blk < ABLK) {
    int n = blk * 16 + (t >> 4);
    int lr = t & 15;
    if (n < N) {
      const float4* xr = (const float4*)(x + (size_t)n * DD);
      float4 va = xr[lr * 2], vb = xr[lr * 2 + 1];
      float m = fmaxf(fmaxf(fmaxf(fabsf(va.x), fabsf(va.y)), fmaxf(fabsf(va.z), fabsf(va.w))),
                      fmaxf(fmaxf(fabsf(vb.x), fabsf(vb.y)), fmaxf(fabsf(vb.z), fabsf(vb.w))));
#pragma unroll
      for (int d = 1; d < 16; d <<= 1) m = fmaxf(m, __shfl_xor(m, d, 16));
      m = fmaxf(m, 1e-20f);
      float inv = 127.0f / m;
      unsigned int q0 = (unsigned int)(__float2int_rn(va.x * inv) + 128);
      unsigned int q1 = (unsigned int)(__float2int_rn(va.y * inv) + 128);
      unsigned int q2 = (unsigned int)(__float2int_rn(va.z * inv) + 128);
      unsigned int q3 = (unsigned int)(__float2int_rn(va.w * inv) + 128);
      unsigned int q4 = (unsigned int)(__float2int_rn(vb.x * inv) + 128);
      unsigned int q5 = (unsigned int)(__float2int_rn(vb.y * inv) + 128);
      unsigned int q6 = (unsigned int)(__float2int_rn(vb.z * inv) + 128);
      unsigned int q7 = (unsigned int)(__float2int_rn(vb.w * inv) + 128);
      uint2 qp;
      qp.x = q0 | (q1 << 8) | (q2 << 16) | (q3 << 24);
      qp.y = q4 | (q5 << 8) | (q6 << 16) | (q7 << 24);
      ((uint2*)xq)[(size_t)n * 16 + lr] = qp;
      if (lr == 0) sx[n] = m * (1.0f / 127.0f);
    }
  } else if (blk < ABLK + BBLK) {
    int e = (blk - ABLK) * 256 + t;
    if (e <= E) {
      if (e == 0) {
        int d0 = dst[0];
        for (int n = 0; n <= d0; ++n) row_start[n] = 0;
      } else if (e == E) {
        for (int n = dst[E - 1] + 1; n <= N; ++n) row_start[n] = E;
      } else {
        int d = dst[e], dp = dst[e - 1];
        for (int n = dp + 1; n <= d; ++n) row_start[n] = e;
      }
    }
  } else {
    int e2 = (blk - ABLK - BBLK) * 256 + t;
    if (e2 < 2 * DD * DD) {
      int j = e2 >> 7, k = e2 & 127;
      float v = (j < DD) ? W[j * DD + k] : KG[k * DD + (j - DD)];
      B[e2] = (unsigned short)cvt_pk_bf16(v, v);
    }
  }
}

// ---------------------------------------------------------------------------
// scatter_agg v5: identical gather; aggb written PRE-SWIZZLED
// (byte off = n*256 + (lr*16 ^ ((n&7)<<4)) -- permutation within the 256B row,
// same coalescing) so fused_gemm can stage it with a LINEAR global_load_lds
// copy and keep the swizzled ds_read pattern (G21 both-sides rule).
// ---------------------------------------------------------------------------
__global__ __launch_bounds__(256, 8) void scatter_agg(
    const unsigned char* __restrict__ xq, const float* __restrict__ sx,
    const int* __restrict__ src, const float* __restrict__ ew,
    const int* __restrict__ row_start, unsigned char* __restrict__ aggb,
    float* __restrict__ sumw, int N, int E) {
  int t = threadIdx.x;
  int wid = t >> 6, lane = t & 63;
  int g = lane >> 4, lr = lane & 15;
  int n = blockIdx.x * 16 + wid * 4 + g;
  bool valid = (n < N);
  int b = valid ? row_start[n] : 0;
  int cnt = valid ? (row_start[n + 1] - b) : 0;
  const uint2* x8 = (const uint2*)xq;

  float a[8];
#pragma unroll
  for (int k = 0; k < 8; ++k) a[k] = 0.f;
  float wsum = 0.f, wsc = 0.f;
  int clampj = cnt > 0 ? cnt - 1 : 0;

  int i = 0;
  while (__any(i < cnt)) {
#pragma unroll
    for (int u = 0; u < 4; ++u) {
      int ii = i + u;
      int jj = ii < clampj ? ii : clampj;
      int j = b + jj;
      if (j > E - 1) j = E - 1;
      float wt = (ii < cnt) ? ew[j] : 0.f;
      int s = src[j];
      float ws = wt * sx[s];
      uint2 v = x8[(size_t)s * 16 + lr];
      wsum += wt;
      wsc += ws;
      a[0] += ws * (float)(v.x & 0xFF);
      a[1] += ws * (float)((v.x >> 8) & 0xFF);
      a[2] += ws * (float)((v.x >> 16) & 0xFF);
      a[3] += ws * (float)(v.x >> 24);
      a[4] += ws * (float)(v.y & 0xFF);
      a[5] += ws * (float)((v.y >> 8) & 0xFF);
      a[6] += ws * (float)((v.y >> 16) & 0xFF);
      a[7] += ws * (float)(v.y >> 24);
    }
    i += 4;
  }
  float c = 128.0f * wsc;
#pragma unroll
  for (int k = 0; k < 8; ++k) a[k] -= c;

  if (valid) {
    uint4 o;
    o.x = cvt_pk_bf16(a[0], a[1]);
    o.y = cvt_pk_bf16(a[2], a[3]);
    o.z = cvt_pk_bf16(a[4], a[5]);
    o.w = cvt_pk_bf16(a[6], a[7]);
    *(uint4*)(aggb + (size_t)n * 256 + ((lr * 16) ^ ((n & 7) << 4))) = o;
    if (lr == 0) sumw[n] = wsum;
  }
}

// ---------------------------------------------------------------------------
// fused_gemm v7: per 64-node tile:
//   S = relu(agg @ W^T + sumw*b);  G = sigmoid(x @ KG + bg);
//   out = G*S + (1-G)*x
// agg tile staged via global_load_lds width=16 (linear copy of the
// pre-swizzled aggb -> no VGPR round-trip), ISSUED FIRST so its latency
// hides under the xq int8->bf16 dequant. Paired NT epilogue stores.
// ---------------------------------------------------------------------------
__global__ __launch_bounds__(256, 3) void fused_gemm(
    const unsigned char* __restrict__ xq, const float* __restrict__ sx,
    const unsigned char* __restrict__ aggb, const unsigned short* __restrict__ B,
    const float* __restrict__ sumw, const float* __restrict__ bias,
    const float* __restrict__ bg, float* __restrict__ out, int N) {
  __shared__ char smem[32 * 1024];
  unsigned short* sX = (unsigned short*)smem;            // 16KB: x tile bf16 (swz)
  unsigned short* sA = (unsigned short*)(smem + 16384);  // 16KB: agg tile (pre-swz)
  int t = threadIdx.x;
  int wid = t >> 6, lane = t & 63;
  int lr = lane & 15, lk2 = lane >> 4;
  int jw = wid * 32;
  int M0 = blockIdx.x * 64;

  // ---- issue agg tile global->LDS copy FIRST (async, 16B/lane, linear)
  {
    const char* gsrc = (const char*)aggb + (size_t)M0 * 256 + wid * 4096 + lane * 16;
    char* ldst = (char*)sA + wid * 4096;  // wave-uniform base
#pragma unroll
    for (int i = 0; i < 4; ++i) {
      __builtin_amdgcn_global_load_lds(
          (const __attribute__((address_space(1))) unsigned int*)(gsrc + i * 1024),
          (__attribute__((address_space(3))) unsigned int*)(ldst + i * 1024),
          16, 0, 0);
    }
  }

  // ---- persistent weight fragments: W rows (support) and KG^T rows (gate)
  bf16x8 wS[4][2], wG[4][2];  // [kc][m]
#pragma unroll
  for (int kc = 0; kc < 4; ++kc)
#pragma unroll
    for (int m = 0; m < 2; ++m) {
      int j = jw + m * 16 + lr;
      wS[kc][m] = *(const bf16x8*)(B + (size_t)j * DD + kc * 32 + lk2 * 8);
      wG[kc][m] = *(const bf16x8*)(B + (size_t)(DD + j) * DD + kc * 32 + lk2 * 8);
    }

  // ---- stage x tile from xq: 512 uint4 (16 int8 each), dequant -> bf16, swz
#pragma unroll
  for (int i = 0; i < 2; ++i) {
    int idx = i * 256 + t;
    int r = idx >> 3;           // row in tile (8 uint4 per 128B row)
    int c = idx & 7;            // 16-byte chunk
    uint4 v;
    float s;
    if (M0 + r < N) {
      v = ((const uint4*)(xq + (size_t)(M0 + r) * DD))[c];
      s = sx[M0 + r];
    } else {
      v = make_uint4(0, 0, 0, 0);
      s = 0.f;
    }
    float nb = -128.0f * s;
    unsigned int w[4] = {v.x, v.y, v.z, v.w};
    unsigned int o[8];
#pragma unroll
    for (int q = 0; q < 4; ++q) {
      float e0 = fmaf(s, (float)(w[q] & 0xFF), nb);
      float e1 = fmaf(s, (float)((w[q] >> 8) & 0xFF), nb);
      float e2 = fmaf(s, (float)((w[q] >> 16) & 0xFF), nb);
      float e3 = fmaf(s, (float)(w[q] >> 24), nb);
      o[q * 2]     = cvt_pk_bf16(e0, e1);
      o[q * 2 + 1] = cvt_pk_bf16(e2, e3);
    }
    int base = r * 256 + c * 32;
    uint4 lo = {o[0], o[1], o[2], o[3]};
    uint4 hi = {o[4], o[5], o[6], o[7]};
    *(uint4*)((char*)sX + ((base) ^ ((r & 7) << 4)))      = lo;
    *(uint4*)((char*)sX + ((base + 16) ^ ((r & 7) << 4))) = hi;
  }
  __syncthreads();   // drains vmcnt (gload_lds) + lgkmcnt

  f32x4 accS[2][4], accG[2][4];
#pragma unroll
  for (int m = 0; m < 2; ++m)
#pragma unroll
    for (int nr = 0; nr < 4; ++nr) {
      accS[m][nr] = (f32x4){0.f, 0.f, 0.f, 0.f};
      accG[m][nr] = (f32x4){0.f, 0.f, 0.f, 0.f};
    }

#pragma unroll
  for (int kc = 0; kc < 4; ++kc) {
    int kb = (kc * 32 + lk2 * 8) * 2;
    bf16x8 af[4], xf[4];
#pragma unroll
    for (int nr = 0; nr < 4; ++nr) {
      int r = nr * 16 + lr;
      int off = (r * 256 + kb) ^ ((r & 7) << 4);
      af[nr] = *(const bf16x8*)((const char*)sA + off);
      xf[nr] = *(const bf16x8*)((const char*)sX + off);
    }
#pragma unroll
    for (int m = 0; m < 2; ++m)
#pragma unroll
      for (int nr = 0; nr < 4; ++nr) {
        accS[m][nr] = __builtin_amdgcn_mfma_f32_16x16x32_bf16(wS[kc][m], af[nr], accS[m][nr], 0, 0, 0);
        accG[m][nr] = __builtin_amdgcn_mfma_f32_16x16x32_bf16(wG[kc][m], xf[nr], accG[m][nr], 0, 0, 0);
      }
  }

  // ---- epilogue: nr outer, m inner -> the two 64B half-row stores pair up.
  float ba[2][4], bga[2][4];
#pragma unroll
  for (int m = 0; m < 2; ++m) {
    int j0 = jw + m * 16 + lk2 * 4;
    *(float4*)ba[m]  = *(const float4*)&bias[j0];
    *(float4*)bga[m] = *(const float4*)&bg[j0];
  }
#pragma unroll
  for (int nr = 0; nr < 4; ++nr) {
    int node = M0 + nr * 16 + lr;
    if (node < N) {
      float sw = sumw[node];
      int r = nr * 16 + lr;
#pragma unroll
      for (int m = 0; m < 2; ++m) {
        int j0 = jw + m * 16 + lk2 * 4;
        uint2 qx = *(const uint2*)((const char*)sX + ((r * 256 + j0 * 2) ^ ((r & 7) << 4)));
        float xr[4] = {bf_lo(qx.x), bf_hi(qx.x), bf_lo(qx.y), bf_hi(qx.y)};
        f32x4 vs = accS[m][nr], vg = accG[m][nr];
        f32x4 o;
#pragma unroll
        for (int reg = 0; reg < 4; ++reg) {
          float s = fmaxf(vs[reg] + sw * ba[m][reg], 0.f);
          float g = 1.0f / (1.0f + __expf(-(vg[reg] + bga[m][reg])));
          o[reg] = g * s + (1.0f - g) * xr[reg];
        }
        __builtin_nontemporal_store(o, (f32x4*)&out[(size_t)node * DD + j0]);
      }
    }
  }
}

// ---------------------------------------------------------------------------
extern "C" void kernel_launch(void* const* d_in, const int* in_sizes, int n_in,
                              void* d_out, int out_size, void* d_ws, size_t ws_size,
                              hipStream_t stream) {
  const float* x   = (const float*)d_in[0];
  const int*   src = (const int*)d_in[1];
  const int*   dst = (const int*)d_in[2];
  const float* ew  = (const float*)d_in[3];
  const float* W   = (const float*)d_in[4];
  const float* b   = (const float*)d_in[5];
  const float* KG  = (const float*)d_in[6];
  const float* bg  = (const float*)d_in[7];
  float* out = (float*)d_out;

  int N = in_sizes[0] / DD;
  int E = in_sizes[1];

  unsigned char* aggb = (unsigned char*)d_ws;              // N rows x 256B (pre-swz bf16)
  unsigned char* xq = aggb + (size_t)N * 256;              // N*128 u8
  float* sx = (float*)(xq + (size_t)N * DD);               // N f32
  float* sumw = sx + N;                                    // N f32
  unsigned short* B = (unsigned short*)(sumw + N);         // 2*128*128 bf16
  int* row_start = (int*)(B + 2 * DD * DD);                // N+1 ints

  int ABLK = (N + 15) / 16;
  int BBLK = (E + 1 + 255) / 256;
  int CBLK = (2 * DD * DD + 255) / 256;
  prep_kernel<<<ABLK + BBLK + CBLK, 256, 0, stream>>>(x, dst, W, KG, xq, sx,
                                                      row_start, B, N, E, ABLK, BBLK);
  scatter_agg<<<(N + 15) / 16, 256, 0, stream>>>(xq, sx, src, ew, row_start, aggb, sumw, N, E);
  fused_gemm<<<(N + 63) / 64, 256, 0, stream>>>(xq, sx, aggb, B, sumw, b, bg, out, N);
}